// Round 7
// baseline (449.964 us; speedup 1.0000x reference)
//
#include <hip/hip_runtime.h>
#include <hip/hip_bf16.h>

typedef __hip_bfloat16 bf16;
typedef __bf16 bf8 __attribute__((ext_vector_type(8)));
typedef float  f4  __attribute__((ext_vector_type(4)));

#define N_ATOMS 25000
#define NE      800000
#define NEA     300000
#define NT      1600000
#define APB     64
#define NBUK    ((N_ATOMS + APB - 1) / APB)   // 391

#define DIN0  376
#define DIN1  616
#define DINP0 384
#define DINP1 640

#define EBLK ((NE + 4095) / 4096)   // 196
#define TBLK ((NT + 4095) / 4096)   // 391

#define NFRAG0 ((DINP0 / 32) * 16 * 64)   // 12288
#define NFRAG1 ((DINP1 / 32) * 16 * 64)   // 20480
#define NFRAGS (8 * 6 * 64)               // 3072

#define S0BLK ((N_ATOMS * 120 + 255) / 256)   // 11719
#define DABLK ((NEA + 255) / 256)             // 1172

__device__ __forceinline__ float tssr2f(float x) {
    float ax = fabsf(x);
    return (ax <= 1.f) ? x : copysignf(2.f * __builtin_sqrtf(ax) - 1.f, x);
}

__device__ __forceinline__ unsigned short f2bf_rn(float v) {
    unsigned int b = __float_as_uint(v);
    b += 0x7FFF + ((b >> 16) & 1);
    return (unsigned short)(b >> 16);
}
__device__ __forceinline__ float bf2f(unsigned short u) {
    return __uint_as_float(((unsigned int)u) << 16);
}

// ------------------------------------------------------------------
// Bucket-granularity count
// ------------------------------------------------------------------
__global__ __launch_bounds__(256) void k_bcount(const int* __restrict__ esrc,
                                                const int* __restrict__ cat,
                                                int* __restrict__ ebcnt,
                                                int* __restrict__ tbcnt) {
    __shared__ int h[NBUK];
    int t = threadIdx.x;
    for (int b = t; b < NBUK; b += 256) h[b] = 0;
    __syncthreads();
    bool isE = blockIdx.x < EBLK;
    const int* key = isE ? esrc : cat;
    int n = isE ? NE : NT;
    int base = (isE ? blockIdx.x : (blockIdx.x - EBLK)) * 4096;
#pragma unroll
    for (int k = 0; k < 16; k++) {
        int idx = base + k * 256 + t;
        if (idx < n) atomicAdd(&h[key[idx] >> 6], 1);
    }
    __syncthreads();
    int* g = isE ? ebcnt : tbcnt;
    for (int b = t; b < NBUK; b += 256)
        if (h[b]) atomicAdd(&g[b], h[b]);
}

// ------------------------------------------------------------------
// Scan 391 bucket counts
// ------------------------------------------------------------------
__global__ __launch_bounds__(512) void k_scanB(const int* cnt0, int* off0, int* cur0,
                                               int* aoff0,
                                               const int* cnt1, int* off1, int* cur1,
                                               int* aoff1) {
    const int* cnt = blockIdx.x ? cnt1 : cnt0;
    int* off  = blockIdx.x ? off1 : off0;
    int* cur  = blockIdx.x ? cur1 : cur0;
    int* aoff = blockIdx.x ? aoff1 : aoff0;
    int nelem = blockIdx.x ? NT : NE;
    __shared__ int sh[512];
    int t = threadIdx.x;
    int v = (t < NBUK) ? cnt[t] : 0;
    sh[t] = v;
    __syncthreads();
    for (int d = 1; d < 512; d <<= 1) {
        int a = (t >= d) ? sh[t - d] : 0;
        __syncthreads();
        sh[t] += a;
        __syncthreads();
    }
    int excl = sh[t] - v;
    if (t <= NBUK) { off[t] = excl; if (t < NBUK) cur[t] = excl; }
    if (t == 0) aoff[N_ATOMS] = nelem;
}

// ------------------------------------------------------------------
// Phase A (merged edges+triplets): bin payloads into coarse buckets.
// Triplets: angle only consumed via cos(angle) -> store cosine.
// ------------------------------------------------------------------
__global__ __launch_bounds__(512) void k_binA2(const float* __restrict__ eA,
                                               const float* __restrict__ eB,
                                               const int* __restrict__ eC,
                                               const int* __restrict__ ekey,
                                               int* __restrict__ egcur,
                                               float4* __restrict__ ebuk,
                                               const float* __restrict__ tA,
                                               const int* __restrict__ tB,
                                               const int* __restrict__ tC,
                                               const int* __restrict__ tkey,
                                               int* __restrict__ tgcur,
                                               float4* __restrict__ tbuk) {
    __shared__ int cnt[NBUK];
    __shared__ int rbase[NBUK];
    int t = threadIdx.x;
    for (int b = t; b < NBUK; b += 512) cnt[b] = 0;
    __syncthreads();
    bool isE = blockIdx.x < EBLK;
    const int* key = isE ? ekey : tkey;
    int n = isE ? NE : NT;
    int* gcur = isE ? egcur : tgcur;
    float4* buk = isE ? ebuk : tbuk;
    int base = (isE ? blockIdx.x : (blockIdx.x - EBLK)) * 4096;
    float4 pay[8];
    int bk[8], off[8];
#pragma unroll
    for (int k = 0; k < 8; k++) {
        int idx = base + k * 512 + t;
        bk[k] = -1;
        if (idx < n) {
            float4 p;
            if (isE) {
                p.x = eA[idx];
                p.y = eB[idx];
                p.z = __int_as_float(eC[idx]);
            } else {
                p.x = __cosf(tA[idx]);
                p.y = __int_as_float(tB[idx]);
                p.z = __int_as_float(tC[idx]);
            }
            int ky = key[idx];
            p.w = __int_as_float(ky);
            pay[k] = p;
            bk[k] = ky >> 6;
            off[k] = atomicAdd(&cnt[bk[k]], 1);
        }
    }
    __syncthreads();
    for (int b = t; b < NBUK; b += 512)
        if (cnt[b]) rbase[b] = atomicAdd(&gcur[b], cnt[b]);
    __syncthreads();
#pragma unroll
    for (int k = 0; k < 8; k++)
        if (bk[k] >= 0) buk[rbase[bk[k]] + off[k]] = pay[k];
}

// ------------------------------------------------------------------
// Phase B (merged): one workgroup per bucket; blocks [0,NBUK) edges,
// [NBUK,2*NBUK) triplets.
// EDGES: compute Bessel rb[8] once (shared by both layers), emit
// erb[NE][8] + edi[NE].
// ------------------------------------------------------------------
__global__ __launch_bounds__(256) void k_binB2(const int* __restrict__ ebkoff,
                                               const float4* __restrict__ ebuk,
                                               float* __restrict__ erb,
                                               int* __restrict__ edi,
                                               int* __restrict__ eoff,
                                               const int* __restrict__ tbkoff,
                                               const float4* __restrict__ tbuk,
                                               float4* __restrict__ tfin,
                                               int* __restrict__ toff) {
    bool isE = blockIdx.x < NBUK;
    int b = isE ? blockIdx.x : (blockIdx.x - NBUK);
    const int* bkoff = isE ? ebkoff : tbkoff;
    const float4* buk = isE ? ebuk : tbuk;
    int* aoff = isE ? eoff : toff;
    int lo = b * APB;
    int hi = min(lo + APB, N_ATOMS);
    __shared__ int cnt[APB];
    __shared__ int cur[APB];
    int t = threadIdx.x;
    if (t < APB) cnt[t] = 0;
    __syncthreads();
    int pbeg = bkoff[b], pend = bkoff[b + 1];
    for (int p = pbeg + t; p < pend; p += 256) {
        int a = __float_as_int(((const float*)(buk + p))[3]);
        atomicAdd(&cnt[a - lo], 1);
    }
    __syncthreads();
    if (t == 0) {
        int run = pbeg;
        for (int k = 0; k < hi - lo; k++) {
            cur[k] = run;
            aoff[lo + k] = run;
            run += cnt[k];
        }
    }
    __syncthreads();
    for (int p = pbeg + t; p < pend; p += 256) {
        float4 pay = buk[p];
        int a = __float_as_int(pay.w);
        int slot = atomicAdd(&cur[a - lo], 1);
        if (isE) {
            float d = pay.x, s = pay.y;
            float q = 0.6324555320f * s / d;
            float r[8];
#pragma unroll
            for (int n = 0; n < 8; n++)
                r[n] = q * __sinf((n + 1) * 0.6283185307f * d);
            *(float4*)&erb[(size_t)slot * 8]     = make_float4(r[0], r[1], r[2], r[3]);
            *(float4*)&erb[(size_t)slot * 8 + 4] = make_float4(r[4], r[5], r[6], r[7]);
            edi[slot] = __float_as_int(pay.z);
        } else {
            tfin[slot] = pay;
        }
    }
}

// ------------------------------------------------------------------
// W -> bf16 fragment layout, all three weight matrices in one launch
// ------------------------------------------------------------------
__device__ __forceinline__ void wprep_one(const float* __restrict__ W, bf8* __restrict__ Wf,
                                          int K, int N, int ntiles, int f) {
    int lane = f & 63;
    int ft = f >> 6;
    int tile = ft % ntiles;
    int chunk = ft / ntiles;
    int n = tile * 16 + (lane & 15);
    int kb = chunk * 32 + (lane >> 4) * 8;
    bf8 v;
#pragma unroll
    for (int j = 0; j < 8; j++) {
        int k = kb + j;
        v[j] = (__bf16)((k < K) ? W[k * N + n] : 0.f);
    }
    Wf[f] = v;
}

__global__ __launch_bounds__(256) void k_wprep3(const float* __restrict__ W0, bf8* __restrict__ Wf0,
                                                const float* __restrict__ W1, bf8* __restrict__ Wf1,
                                                const float* __restrict__ WS, bf8* __restrict__ WfS) {
    int f = blockIdx.x * 256 + threadIdx.x;
    if (f < NFRAG0) {
        wprep_one(W0, Wf0, DIN0, 256, 16, f);
    } else if (f < NFRAG0 + NFRAG1) {
        wprep_one(W1, Wf1, DIN1, 256, 16, f - NFRAG0);
    } else if (f < NFRAG0 + NFRAG1 + NFRAGS) {
        wprep_one(WS, WfS, 256, 96, 6, f - NFRAG0 - NFRAG1);
    }
}

// ------------------------------------------------------------------
// k_pre (merged): blocks [0,S0BLK) = layer-0 species/si fill;
// blocks [S0BLK, S0BLK+DABLK) = da for BOTH layers (8 sins computed
// once, two 8x8 matmuls -> dah0, dah1).
// ------------------------------------------------------------------
__global__ __launch_bounds__(256) void k_pre(const int* __restrict__ sp,
                                             const float* __restrict__ table,
                                             const float* __restrict__ W,
                                             float* __restrict__ ei0,
                                             float* __restrict__ sd,
                                             const float* __restrict__ dist,
                                             const float* __restrict__ sw,
                                             const float* __restrict__ Wda0,
                                             const float* __restrict__ Wda1,
                                             unsigned short* __restrict__ dah0,
                                             unsigned short* __restrict__ dah1) {
    if ((int)blockIdx.x < S0BLK) {
        int idx = blockIdx.x * 256 + threadIdx.x;
        if (idx >= N_ATOMS * 120) return;
        int i = idx / 120;
        int c = idx - i * 120;
        if (c >= 112) {
            ei0[(size_t)i * DINP0 + 376 + (c - 112)] = 0.f;
            return;
        }
        int s = sp[i];
        if (c < 16) {
            ei0[(size_t)i * DINP0 + c] = table[s * 16 + c];
        } else {
            int cc = c - 16;
            float acc = 0.f;
#pragma unroll
            for (int k = 0; k < 16; k++)
                acc += table[s * 16 + k] * W[k * 96 + cc];
            if (cc < 64) ei0[(size_t)i * DINP0 + 16 + cc] = acc;
            else         sd[i * 32 + cc - 64]             = acc;
        }
    } else {
        int e = (blockIdx.x - S0BLK) * 256 + threadIdx.x;
        if (e >= NEA) return;
        float d = dist[e];
        float s = sw[e];
        float rb[8];
#pragma unroll
        for (int n = 0; n < 8; n++)
            rb[n] = 0.7559289460f * __sinf((n + 1) * 0.8975979010f * d) / d * s;
        unsigned short h0[8], h1[8];
#pragma unroll
        for (int c = 0; c < 8; c++) {
            float a0 = 0.f, a1 = 0.f;
#pragma unroll
            for (int n = 0; n < 8; n++) {
                a0 += rb[n] * Wda0[n * 8 + c];
                a1 += rb[n] * Wda1[n * 8 + c];
            }
            h0[c] = f2bf_rn(a0);
            h1[c] = f2bf_rn(a1);
        }
        *(uint4*)&dah0[e * 8] = *(uint4*)h0;
        *(uint4*)&dah1[e * 8] = *(uint4*)h1;
    }
}

// ------------------------------------------------------------------
// layer 1 s: MFMA GEMM 25000x96
// ------------------------------------------------------------------
__global__ __launch_bounds__(256) void k_s1(const float* __restrict__ ei1,
                                            const bf8* __restrict__ Wf,
                                            float* __restrict__ ei1o,
                                            float* __restrict__ sd) {
    __shared__ __align__(16) __bf16 Asg[4][64][8];
    int t = threadIdx.x;
    int w = t >> 6, lane = t & 63;
    int a0 = blockIdx.x * 64;

    int satom = a0 + (t >> 2);
    int k8 = (t & 3) * 8;
    const float* arow = &ei1[(size_t)satom * DINP1 + k8];
    bool aok = satom < N_ATOMS;
    int dw = (t >> 2) >> 4;
    int dl = ((t >> 2) & 15) | ((t & 3) << 4);
    __bf16* adst = &Asg[dw][dl][0];

    f4 acc[6];
#pragma unroll
    for (int j = 0; j < 6; j++) {
        f4 z = {0.f, 0.f, 0.f, 0.f};
        acc[j] = z;
    }

    for (int ch = 0; ch < 8; ch++) {
        float4 v0 = make_float4(0.f, 0.f, 0.f, 0.f);
        float4 v1 = make_float4(0.f, 0.f, 0.f, 0.f);
        if (aok) {
            v0 = *(const float4*)(arow + ch * 32);
            v1 = *(const float4*)(arow + ch * 32 + 4);
        }
        __syncthreads();
        adst[0] = (__bf16)v0.x; adst[1] = (__bf16)v0.y;
        adst[2] = (__bf16)v0.z; adst[3] = (__bf16)v0.w;
        adst[4] = (__bf16)v1.x; adst[5] = (__bf16)v1.y;
        adst[6] = (__bf16)v1.z; adst[7] = (__bf16)v1.w;
        __syncthreads();
        bf8 afr = *(const bf8*)&Asg[w][lane][0];
        const bf8* wp = &Wf[(ch * 6) * 64 + lane];
#pragma unroll
        for (int tn = 0; tn < 6; tn++) {
            bf8 b = wp[tn * 64];
            acc[tn] = __builtin_amdgcn_mfma_f32_16x16x32_bf16(afr, b, acc[tn], 0, 0, 0);
        }
    }

    int nlo = lane & 15, q = lane >> 4;
#pragma unroll
    for (int r = 0; r < 4; r++) {
        int atom = a0 + w * 16 + q * 4 + r;
        if (atom < N_ATOMS) {
#pragma unroll
            for (int tn = 0; tn < 6; tn++) {
                int col = tn * 16 + nlo;
                float v = acc[tn][r];
                if (col < 64) ei1o[(size_t)atom * DINP1 + 256 + col] = v;
                else          sd[atom * 32 + col - 64] = v;
            }
        }
    }
    for (int z = t; z < 64 * 24; z += 256) {
        int za = a0 + z / 24;
        if (za < N_ATOMS) ei1o[(size_t)za * DINP1 + 616 + z % 24] = 0.f;
    }
}

// ------------------------------------------------------------------
// ami window helper: process up to 64 triplets held in twA (this
// wave's coalesced window), limit lim, with 1-deep dah prefetch.
// ------------------------------------------------------------------
__device__ __forceinline__ void ami_win(const float4 twA, const unsigned short* __restrict__ dah,
                                        int lim, int jj, int c,
                                        float& a0, float& a1, float& a2, float& a3, float& a4) {
    int gmax = (lim + 7) >> 3;
    float sc = 0.f; unsigned short dA = 0, dB = 0;
    {
        sc = __shfl(twA.x, jj, 64);
        int ea = __float_as_int(__shfl(twA.y, jj, 64));
        int eb = __float_as_int(__shfl(twA.z, jj, 64));
        dA = dah[ea * 8 + c];
        dB = dah[eb * 8 + c];
    }
    for (int g = 0; g < gmax; g++) {
        float scN = 0.f; unsigned short dAN = 0, dBN = 0;
        if (g + 1 < gmax) {
            int sl = (g + 1) * 8 + jj;
            scN = __shfl(twA.x, sl, 64);
            int ea = __float_as_int(__shfl(twA.y, sl, 64));
            int eb = __float_as_int(__shfl(twA.z, sl, 64));
            dAN = dah[ea * 8 + c];
            dBN = dah[eb * 8 + c];
        }
        float dij = bf2f(dA) * bf2f(dB);
        dij = (g * 8 + jj < lim) ? dij : 0.f;
        float c1 = sc;
        float c2 = __builtin_fmaf(2.f * c1, c1, -1.f);
        float c3 = __builtin_fmaf(2.f * c1, c2, -c1);
        float c4 = __builtin_fmaf(2.f * c1, c3, -c2);
        a0 += dij;
        a1 = __builtin_fmaf(c1, dij, a1);
        a2 = __builtin_fmaf(c2, dij, a2);
        a3 = __builtin_fmaf(c3, dij, a3);
        a4 = __builtin_fmaf(c4, dij, a4);
        if (g + 1 < gmax) { sc = scN; dA = dAN; dB = dBN; }
    }
}

// ------------------------------------------------------------------
// k_seg v2 (merged mi+ami): blocks [0,N_ATOMS) = mi, rest = ami.
// ONE atom per 256-thread block, FOUR waves per atom (r5-proven TLP
// split, deepened): typical mi atom (cnt=32, nG=4) gives each wave
// exactly ONE group -> one exposed gather chain per wave instead of
// two; ami (cnt=64) gives 2 groups/wave with the internal 1-deep
// prefetch covering the second. Per-wave coalesced windows extend the
// fast path to cnt<=256. Partials combined via LDS in fixed order;
// barrier-safe (no early return before __syncthreads). No VGPR-cap
// (r4 lesson); per-wave state unchanged (~55 VGPR, under the 64 cliff).
// ------------------------------------------------------------------
__global__ __launch_bounds__(256) void k_seg(const int* __restrict__ eoff,
                                             const float* __restrict__ erb,
                                             const int* __restrict__ edi,
                                             const float* __restrict__ sd,
                                             float* __restrict__ mo, int mstride,
                                             const int* __restrict__ toff,
                                             const float4* __restrict__ tpay,
                                             const unsigned short* __restrict__ dah,
                                             float* __restrict__ ao, int astride) {
    __shared__ float4 smi[3][64];
    __shared__ float  sam[3][5][8];
    int t = threadIdx.x;
    int p = t >> 6, l = t & 63;

    if ((int)blockIdx.x < N_ATOMS) {
        // ---------------- mi ----------------
        int i = blockIdx.x;
        int beg = eoff[i], end = eoff[i + 1];
        int cnt = end - beg;
        int n = l >> 3, cb = (l & 7) * 4;
        float4 acc = make_float4(0.f, 0.f, 0.f, 0.f);

        if (cnt > 0) {
            int nG = (cnt + 7) >> 3;
            int h = (nG + 3) >> 2;          // groups per wave
            if (cnt <= 256) {
                // per-wave window: wave p owns edges [tb, te), <=64 wide
                int tb = p * h * 8;
                int te = min(tb + h * 8, cnt);
                int mycnt = te - tb;
                if (mycnt > 0) {
                    int b0 = beg + tb;
                    int eWin = edi[b0 + min(l, mycnt - 1)];
                    int gmax = (mycnt + 7) >> 3;
                    int cmax = end * 8 - 1;
                    float cA = erb[min(b0 * 8 + l, cmax)];
                    for (int g = 0; g < gmax; g++) {
                        int e8 = g * 8;
                        float4 v[8];
#pragma unroll
                        for (int j = 0; j < 8; j++) {
                            int eid = __shfl(eWin, e8 + j, 64);
                            v[j] = *(const float4*)&sd[eid * 32 + cb];
                        }
                        float cB = 0.f;
                        if (g + 1 < gmax) cB = erb[min((b0 + e8 + 8) * 8 + l, cmax)];
#pragma unroll
                        for (int j = 0; j < 8; j++) {
                            float r_ = __shfl(cA, j * 8 + n, 64);
                            r_ = (e8 + j < mycnt) ? r_ : 0.f;
                            acc.x += r_ * v[j].x; acc.y += r_ * v[j].y;
                            acc.z += r_ * v[j].z; acc.w += r_ * v[j].w;
                        }
                        if (g + 1 < gmax) cA = cB;
                    }
                }
            } else {
                // ultra-rare path: direct indexed loads, quarter of groups
                int gbeg = min(p * h, nG);
                int gend = min(gbeg + h, nG);
                const float* rp = erb + (size_t)beg * 8 + n;
                const int*   dp = edi + beg;
                for (int g = gbeg; g < gend; g++) {
                    int e8 = g * 8;
                    int m = cnt - e8;   // >= 1
#pragma unroll
                    for (int j = 0; j < 8; j++) {
                        int jj = min(j, m - 1);
                        float rb = rp[(e8 + jj) * 8];
                        int di = dp[e8 + jj];
                        if (j >= m) rb = 0.f;
                        float4 v = *(const float4*)&sd[di * 32 + cb];
                        acc.x += rb * v.x; acc.y += rb * v.y;
                        acc.z += rb * v.z; acc.w += rb * v.w;
                    }
                }
            }
        }

        if (p) smi[p - 1][l] = acc;
        __syncthreads();
        if (p == 0) {
            float4 q1 = smi[0][l], q2 = smi[1][l], q3 = smi[2][l];
            acc.x = acc.x + q1.x + q2.x + q3.x;
            acc.y = acc.y + q1.y + q2.y + q3.y;
            acc.z = acc.z + q1.z + q2.z + q3.z;
            acc.w = acc.w + q1.w + q2.w + q3.w;
            *(float4*)&mo[(size_t)i * mstride + l * 4] = acc;   // n*32+cb == l*4
        }
    } else {
        // ---------------- ami ----------------
        int i = (int)blockIdx.x - N_ATOMS;
        int beg = toff[i], end = toff[i + 1];
        int cnt = end - beg;
        int jj = l >> 3, c = l & 7;
        float a0 = 0.f, a1 = 0.f, a2 = 0.f, a3 = 0.f, a4 = 0.f;

        if (cnt > 0) {
            int nG = (cnt + 7) >> 3;
            int h = (nG + 3) >> 2;
            if (cnt <= 256) {
                int tb = p * h * 8;
                int te = min(tb + h * 8, cnt);
                int mycnt = te - tb;
                if (mycnt > 0) {
                    float4 twA = tpay[beg + tb + min(l, mycnt - 1)];
                    ami_win(twA, dah, mycnt, jj, c, a0, a1, a2, a3, a4);
                }
            } else {
                // ultra-rare: 64-windows strided across the 4 waves
                int nW = (cnt + 63) >> 6;
                for (int W = p; W < nW; W += 4) {
                    int wbase = W * 64;
                    int rem = cnt - wbase;
                    int lim = min(rem, 64);
                    float4 twA = tpay[beg + wbase + min(l, rem - 1)];
                    ami_win(twA, dah, lim, jj, c, a0, a1, a2, a3, a4);
                }
            }
        }

        // reduce over jj within wave (lanes l, l^8, l^16, l^32)
#pragma unroll
        for (int msk = 8; msk <= 32; msk <<= 1) {
            a0 += __shfl_xor(a0, msk, 64);
            a1 += __shfl_xor(a1, msk, 64);
            a2 += __shfl_xor(a2, msk, 64);
            a3 += __shfl_xor(a3, msk, 64);
            a4 += __shfl_xor(a4, msk, 64);
        }
        if (p && l < 8) {
            sam[p - 1][0][l] = a0; sam[p - 1][1][l] = a1; sam[p - 1][2][l] = a2;
            sam[p - 1][3][l] = a3; sam[p - 1][4][l] = a4;
        }
        __syncthreads();
        if (p == 0 && l < 8) {
            a0 = a0 + sam[0][0][l] + sam[1][0][l] + sam[2][0][l];
            a1 = a1 + sam[0][1][l] + sam[1][1][l] + sam[2][1][l];
            a2 = a2 + sam[0][2][l] + sam[1][2][l] + sam[2][2][l];
            a3 = a3 + sam[0][3][l] + sam[1][3][l] + sam[2][3][l];
            a4 = a4 + sam[0][4][l] + sam[1][4][l] + sam[2][4][l];
            float* o = &ao[(size_t)i * astride + c];
            o[0]  = a0;
            o[8]  = a1;
            o[16] = a2;
            o[24] = a3;
            o[32] = a4;
        }
    }
}

// ------------------------------------------------------------------
// MFMA GEMM: dxi = tssr2(ei @ W + b)
// ------------------------------------------------------------------
template <int LAYER>
__global__ __launch_bounds__(256) void k_gemm(const float* __restrict__ ei,
                                              const bf8* __restrict__ Wf,
                                              const float* __restrict__ bias,
                                              const float* __restrict__ skip,
                                              float* __restrict__ out) {
    constexpr int DINP = (LAYER == 0) ? DINP0 : DINP1;
    constexpr int NCH = DINP / 32;
    __shared__ __align__(16) __bf16 Asg[2][64][8];
    int t = threadIdx.x;
    int w = t >> 6, lane = t & 63;
    int a0 = blockIdx.x * 32;

    int f  = t * 4;
    int tA = f >> 9;
    int al = (f >> 3) & 63;
    int j0 = f & 7;
    int sm = al & 15, sq = al >> 4;
    int ga = a0 + tA * 16 + sm;
    const float* arow = &ei[(size_t)ga * DINP + sq * 8 + j0];
    __bf16* adst = &Asg[0][0][0] + f;
    bool aok = (ga < N_ATOMS);

    f4 acc[2][4];
#pragma unroll
    for (int i = 0; i < 2; i++)
#pragma unroll
        for (int j = 0; j < 4; j++) {
            f4 z = {0.f, 0.f, 0.f, 0.f};
            acc[i][j] = z;
        }

    for (int ch = 0; ch < NCH; ch++) {
        float4 v = make_float4(0.f, 0.f, 0.f, 0.f);
        if (aok) v = *(const float4*)(arow + ch * 32);
        __syncthreads();
        adst[0] = (__bf16)v.x; adst[1] = (__bf16)v.y;
        adst[2] = (__bf16)v.z; adst[3] = (__bf16)v.w;
        __syncthreads();
        bf8 afr0 = *(const bf8*)&Asg[0][lane][0];
        bf8 afr1 = *(const bf8*)&Asg[1][lane][0];
        const bf8* wp = &Wf[(ch * 16 + w * 4) * 64 + lane];
#pragma unroll
        for (int tn = 0; tn < 4; tn++) {
            bf8 b = wp[tn * 64];
            acc[0][tn] = __builtin_amdgcn_mfma_f32_16x16x32_bf16(afr0, b, acc[0][tn], 0, 0, 0);
            acc[1][tn] = __builtin_amdgcn_mfma_f32_16x16x32_bf16(afr1, b, acc[1][tn], 0, 0, 0);
        }
    }

    int nlo = lane & 15, q = lane >> 4;
#pragma unroll
    for (int tA2 = 0; tA2 < 2; tA2++) {
#pragma unroll
        for (int r = 0; r < 4; r++) {
            int atom = a0 + tA2 * 16 + q * 4 + r;
            if (atom < N_ATOMS) {
#pragma unroll
                for (int tn = 0; tn < 4; tn++) {
                    int col = w * 64 + tn * 16 + nlo;
                    float vv = tssr2f(acc[tA2][tn][r] + bias[col]);
                    if (LAYER == 0) {
                        out[(size_t)atom * DINP1 + col] = vv;
                    } else {
                        out[(size_t)atom * 256 + col] = vv + skip[(size_t)atom * DINP1 + col];
                    }
                }
            }
        }
    }
}

// ------------------------------------------------------------------
extern "C" void kernel_launch(void* const* d_in, const int* in_sizes, int n_in,
                              void* d_out, int out_size, void* d_ws, size_t ws_size,
                              hipStream_t stream) {
    const int*   species     = (const int*)d_in[0];
    const int*   edge_src    = (const int*)d_in[1];
    const int*   edge_dst    = (const int*)d_in[2];
    const float* distances   = (const float*)d_in[3];
    const float* sw          = (const float*)d_in[4];
    const float* angles      = (const float*)d_in[5];
    const int*   angle_src   = (const int*)d_in[6];
    const int*   angle_dst   = (const int*)d_in[7];
    const int*   central     = (const int*)d_in[8];
    const float* dist_a      = (const float*)d_in[9];
    const float* sw_a        = (const float*)d_in[10];
    const float* table       = (const float*)d_in[11];
    const float* W_si0       = (const float*)d_in[12];
    const float* W_si1       = (const float*)d_in[13];
    const float* W_da0       = (const float*)d_in[14];
    const float* W_da1       = (const float*)d_in[15];
    const float* W_mix0      = (const float*)d_in[16];
    const float* b_mix0      = (const float*)d_in[17];
    const float* W_mix1      = (const float*)d_in[18];
    const float* b_mix1      = (const float*)d_in[19];
    float* out = (float*)d_out;

    char* p = (char*)d_ws;
    auto alloc = [&](size_t bytes) {
        char* r = p;
        p += (bytes + 255) & ~(size_t)255;
        return (void*)r;
    };
    float*  ei0  = (float*)alloc((size_t)N_ATOMS * DINP0 * 4);
    float*  ei1  = (float*)alloc((size_t)N_ATOMS * DINP1 * 4);
    float*  sd   = (float*)alloc((size_t)N_ATOMS * 32 * 4);
    unsigned short* dah0 = (unsigned short*)alloc((size_t)NEA * 8 * 2);
    unsigned short* dah1 = (unsigned short*)alloc((size_t)NEA * 8 * 2);
    float*  erbf = (float*)alloc((size_t)NE * 8 * 4);
    int*    edi  = (int*)alloc((size_t)NE * 4);
    float4* tpay = (float4*)alloc((size_t)NT * 16);
    bf8*    Wf0  = (bf8*)alloc((size_t)NFRAG0 * 16);
    bf8*    Wf1  = (bf8*)alloc((size_t)NFRAG1 * 16);
    bf8*    WfS1 = (bf8*)alloc((size_t)NFRAGS * 16);
    int* eoff   = (int*)alloc((size_t)(N_ATOMS + 1) * 4);
    int* toff   = (int*)alloc((size_t)(N_ATOMS + 1) * 4);
    int* bcnt   = (int*)alloc((size_t)2 * NBUK * 4);   // ebcnt | tbcnt (one memset)
    int* ebkoff = (int*)alloc((size_t)(NBUK + 1) * 4);
    int* tbkoff = (int*)alloc((size_t)(NBUK + 1) * 4);
    int* gce    = (int*)alloc((size_t)NBUK * 4);
    int* gct    = (int*)alloc((size_t)NBUK * 4);
    (void)ws_size;
    int* ebcnt = bcnt;
    int* tbcnt = bcnt + NBUK;

    // bucket staging arrays alias ei1 (written only later by k_gemm<0>)
    float4* tbuk = (float4*)ei1;
    float4* ebuk = (float4*)((char*)ei1 + (size_t)NT * 16);

    hipMemsetAsync(bcnt, 0, (size_t)2 * NBUK * 4, stream);

    k_wprep3<<<(NFRAG0 + NFRAG1 + NFRAGS + 255) / 256, 256, 0, stream>>>(
        W_mix0, Wf0, W_mix1, Wf1, W_si1, WfS1);

    k_bcount<<<EBLK + TBLK, 256, 0, stream>>>(edge_src, central, ebcnt, tbcnt);
    k_scanB<<<2, 512, 0, stream>>>(ebcnt, ebkoff, gce, eoff, tbcnt, tbkoff, gct, toff);

    k_binA2<<<EBLK + TBLK, 512, 0, stream>>>(
        distances, sw, edge_dst, edge_src, gce, ebuk,
        angles, angle_src, angle_dst, central, gct, tbuk);
    k_binB2<<<2 * NBUK, 256, 0, stream>>>(
        ebkoff, ebuk, erbf, edi, eoff,
        tbkoff, tbuk, tpay, toff);

    k_pre<<<S0BLK + DABLK, 256, 0, stream>>>(
        species, table, W_si0, ei0, sd,
        dist_a, sw_a, W_da0, W_da1, dah0, dah1);

    int gemm_grid = (N_ATOMS + 31) / 32;

    // ---- layer 0 ----
    k_seg<<<2 * N_ATOMS, 256, 0, stream>>>(eoff, erbf, edi, sd, ei0 + 80, DINP0,
                                           toff, tpay, dah0, ei0 + 336, DINP0);
    k_gemm<0><<<gemm_grid, 256, 0, stream>>>(ei0, Wf0, b_mix0, nullptr, ei1);

    // ---- layer 1 ----
    k_s1<<<(N_ATOMS + 63) / 64, 256, 0, stream>>>(ei1, WfS1, ei1, sd);
    k_seg<<<2 * N_ATOMS, 256, 0, stream>>>(eoff, erbf, edi, sd, ei1 + 320, DINP1,
                                           toff, tpay, dah1, ei1 + 576, DINP1);
    k_gemm<1><<<gemm_grid, 256, 0, stream>>>(ei1, Wf1, b_mix1, ei1, out);
}

// Round 8
// 412.240 us; speedup vs baseline: 1.0915x; 1.0915x over previous
//
#include <hip/hip_runtime.h>
#include <hip/hip_bf16.h>

typedef __hip_bfloat16 bf16;
typedef __bf16 bf8 __attribute__((ext_vector_type(8)));
typedef float  f4  __attribute__((ext_vector_type(4)));

#define N_ATOMS 25000
#define NE      800000
#define NEA     300000
#define NT      1600000
#define APB     64
#define NBUK    ((N_ATOMS + APB - 1) / APB)   // 391

#define DIN0  376
#define DIN1  616
#define DINP0 384
#define DINP1 640

#define EBLK ((NE + 4095) / 4096)   // 196
#define TBLK ((NT + 4095) / 4096)   // 391

#define NFRAG0 ((DINP0 / 32) * 16 * 64)   // 12288
#define NFRAG1 ((DINP1 / 32) * 16 * 64)   // 20480
#define NFRAGS (8 * 6 * 64)               // 3072

#define S0BLK ((N_ATOMS * 120 + 255) / 256)   // 11719
#define DABLK ((NEA + 255) / 256)             // 1172

#define MIBLK ((N_ATOMS + 1) / 2)   // 12500

__device__ __forceinline__ float tssr2f(float x) {
    float ax = fabsf(x);
    return (ax <= 1.f) ? x : copysignf(2.f * __builtin_sqrtf(ax) - 1.f, x);
}

__device__ __forceinline__ unsigned short f2bf_rn(float v) {
    unsigned int b = __float_as_uint(v);
    b += 0x7FFF + ((b >> 16) & 1);
    return (unsigned short)(b >> 16);
}
__device__ __forceinline__ float bf2f(unsigned short u) {
    return __uint_as_float(((unsigned int)u) << 16);
}

// ------------------------------------------------------------------
// Bucket-granularity count
// ------------------------------------------------------------------
__global__ __launch_bounds__(256) void k_bcount(const int* __restrict__ esrc,
                                                const int* __restrict__ cat,
                                                int* __restrict__ ebcnt,
                                                int* __restrict__ tbcnt) {
    __shared__ int h[NBUK];
    int t = threadIdx.x;
    for (int b = t; b < NBUK; b += 256) h[b] = 0;
    __syncthreads();
    bool isE = blockIdx.x < EBLK;
    const int* key = isE ? esrc : cat;
    int n = isE ? NE : NT;
    int base = (isE ? blockIdx.x : (blockIdx.x - EBLK)) * 4096;
#pragma unroll
    for (int k = 0; k < 16; k++) {
        int idx = base + k * 256 + t;
        if (idx < n) atomicAdd(&h[key[idx] >> 6], 1);
    }
    __syncthreads();
    int* g = isE ? ebcnt : tbcnt;
    for (int b = t; b < NBUK; b += 256)
        if (h[b]) atomicAdd(&g[b], h[b]);
}

// ------------------------------------------------------------------
// Scan 391 bucket counts
// ------------------------------------------------------------------
__global__ __launch_bounds__(512) void k_scanB(const int* cnt0, int* off0, int* cur0,
                                               int* aoff0,
                                               const int* cnt1, int* off1, int* cur1,
                                               int* aoff1) {
    const int* cnt = blockIdx.x ? cnt1 : cnt0;
    int* off  = blockIdx.x ? off1 : off0;
    int* cur  = blockIdx.x ? cur1 : cur0;
    int* aoff = blockIdx.x ? aoff1 : aoff0;
    int nelem = blockIdx.x ? NT : NE;
    __shared__ int sh[512];
    int t = threadIdx.x;
    int v = (t < NBUK) ? cnt[t] : 0;
    sh[t] = v;
    __syncthreads();
    for (int d = 1; d < 512; d <<= 1) {
        int a = (t >= d) ? sh[t - d] : 0;
        __syncthreads();
        sh[t] += a;
        __syncthreads();
    }
    int excl = sh[t] - v;
    if (t <= NBUK) { off[t] = excl; if (t < NBUK) cur[t] = excl; }
    if (t == 0) aoff[N_ATOMS] = nelem;
}

// ------------------------------------------------------------------
// Phase A (merged edges+triplets): bin payloads into coarse buckets.
// Triplets: angle only consumed via cos(angle) -> store cosine.
// ------------------------------------------------------------------
__global__ __launch_bounds__(512) void k_binA2(const float* __restrict__ eA,
                                               const float* __restrict__ eB,
                                               const int* __restrict__ eC,
                                               const int* __restrict__ ekey,
                                               int* __restrict__ egcur,
                                               float4* __restrict__ ebuk,
                                               const float* __restrict__ tA,
                                               const int* __restrict__ tB,
                                               const int* __restrict__ tC,
                                               const int* __restrict__ tkey,
                                               int* __restrict__ tgcur,
                                               float4* __restrict__ tbuk) {
    __shared__ int cnt[NBUK];
    __shared__ int rbase[NBUK];
    int t = threadIdx.x;
    for (int b = t; b < NBUK; b += 512) cnt[b] = 0;
    __syncthreads();
    bool isE = blockIdx.x < EBLK;
    const int* key = isE ? ekey : tkey;
    int n = isE ? NE : NT;
    int* gcur = isE ? egcur : tgcur;
    float4* buk = isE ? ebuk : tbuk;
    int base = (isE ? blockIdx.x : (blockIdx.x - EBLK)) * 4096;
    float4 pay[8];
    int bk[8], off[8];
#pragma unroll
    for (int k = 0; k < 8; k++) {
        int idx = base + k * 512 + t;
        bk[k] = -1;
        if (idx < n) {
            float4 p;
            if (isE) {
                p.x = eA[idx];
                p.y = eB[idx];
                p.z = __int_as_float(eC[idx]);
            } else {
                p.x = __cosf(tA[idx]);
                p.y = __int_as_float(tB[idx]);
                p.z = __int_as_float(tC[idx]);
            }
            int ky = key[idx];
            p.w = __int_as_float(ky);
            pay[k] = p;
            bk[k] = ky >> 6;
            off[k] = atomicAdd(&cnt[bk[k]], 1);
        }
    }
    __syncthreads();
    for (int b = t; b < NBUK; b += 512)
        if (cnt[b]) rbase[b] = atomicAdd(&gcur[b], cnt[b]);
    __syncthreads();
#pragma unroll
    for (int k = 0; k < 8; k++)
        if (bk[k] >= 0) buk[rbase[bk[k]] + off[k]] = pay[k];
}

// ------------------------------------------------------------------
// Phase B (merged): one workgroup per bucket; blocks [0,NBUK) edges,
// [NBUK,2*NBUK) triplets.
// EDGES: compute Bessel rb[8] once (shared by both layers), emit
// erb[NE][8] + edi[NE].
// ------------------------------------------------------------------
__global__ __launch_bounds__(256) void k_binB2(const int* __restrict__ ebkoff,
                                               const float4* __restrict__ ebuk,
                                               float* __restrict__ erb,
                                               int* __restrict__ edi,
                                               int* __restrict__ eoff,
                                               const int* __restrict__ tbkoff,
                                               const float4* __restrict__ tbuk,
                                               float4* __restrict__ tfin,
                                               int* __restrict__ toff) {
    bool isE = blockIdx.x < NBUK;
    int b = isE ? blockIdx.x : (blockIdx.x - NBUK);
    const int* bkoff = isE ? ebkoff : tbkoff;
    const float4* buk = isE ? ebuk : tbuk;
    int* aoff = isE ? eoff : toff;
    int lo = b * APB;
    int hi = min(lo + APB, N_ATOMS);
    __shared__ int cnt[APB];
    __shared__ int cur[APB];
    int t = threadIdx.x;
    if (t < APB) cnt[t] = 0;
    __syncthreads();
    int pbeg = bkoff[b], pend = bkoff[b + 1];
    for (int p = pbeg + t; p < pend; p += 256) {
        int a = __float_as_int(((const float*)(buk + p))[3]);
        atomicAdd(&cnt[a - lo], 1);
    }
    __syncthreads();
    if (t == 0) {
        int run = pbeg;
        for (int k = 0; k < hi - lo; k++) {
            cur[k] = run;
            aoff[lo + k] = run;
            run += cnt[k];
        }
    }
    __syncthreads();
    for (int p = pbeg + t; p < pend; p += 256) {
        float4 pay = buk[p];
        int a = __float_as_int(pay.w);
        int slot = atomicAdd(&cur[a - lo], 1);
        if (isE) {
            float d = pay.x, s = pay.y;
            float q = 0.6324555320f * s / d;
            float r[8];
#pragma unroll
            for (int n = 0; n < 8; n++)
                r[n] = q * __sinf((n + 1) * 0.6283185307f * d);
            *(float4*)&erb[(size_t)slot * 8]     = make_float4(r[0], r[1], r[2], r[3]);
            *(float4*)&erb[(size_t)slot * 8 + 4] = make_float4(r[4], r[5], r[6], r[7]);
            edi[slot] = __float_as_int(pay.z);
        } else {
            tfin[slot] = pay;
        }
    }
}

// ------------------------------------------------------------------
// W -> bf16 fragment layout, all three weight matrices in one launch
// ------------------------------------------------------------------
__device__ __forceinline__ void wprep_one(const float* __restrict__ W, bf8* __restrict__ Wf,
                                          int K, int N, int ntiles, int f) {
    int lane = f & 63;
    int ft = f >> 6;
    int tile = ft % ntiles;
    int chunk = ft / ntiles;
    int n = tile * 16 + (lane & 15);
    int kb = chunk * 32 + (lane >> 4) * 8;
    bf8 v;
#pragma unroll
    for (int j = 0; j < 8; j++) {
        int k = kb + j;
        v[j] = (__bf16)((k < K) ? W[k * N + n] : 0.f);
    }
    Wf[f] = v;
}

__global__ __launch_bounds__(256) void k_wprep3(const float* __restrict__ W0, bf8* __restrict__ Wf0,
                                                const float* __restrict__ W1, bf8* __restrict__ Wf1,
                                                const float* __restrict__ WS, bf8* __restrict__ WfS) {
    int f = blockIdx.x * 256 + threadIdx.x;
    if (f < NFRAG0) {
        wprep_one(W0, Wf0, DIN0, 256, 16, f);
    } else if (f < NFRAG0 + NFRAG1) {
        wprep_one(W1, Wf1, DIN1, 256, 16, f - NFRAG0);
    } else if (f < NFRAG0 + NFRAG1 + NFRAGS) {
        wprep_one(WS, WfS, 256, 96, 6, f - NFRAG0 - NFRAG1);
    }
}

// ------------------------------------------------------------------
// k_pre (merged): blocks [0,S0BLK) = layer-0 species/si fill (ei0 is
// bf16 now); blocks [S0BLK, S0BLK+DABLK) = da for BOTH layers.
// ------------------------------------------------------------------
__global__ __launch_bounds__(256) void k_pre(const int* __restrict__ sp,
                                             const float* __restrict__ table,
                                             const float* __restrict__ W,
                                             unsigned short* __restrict__ ei0,
                                             float* __restrict__ sd,
                                             const float* __restrict__ dist,
                                             const float* __restrict__ sw,
                                             const float* __restrict__ Wda0,
                                             const float* __restrict__ Wda1,
                                             unsigned short* __restrict__ dah0,
                                             unsigned short* __restrict__ dah1) {
    if ((int)blockIdx.x < S0BLK) {
        int idx = blockIdx.x * 256 + threadIdx.x;
        if (idx >= N_ATOMS * 120) return;
        int i = idx / 120;
        int c = idx - i * 120;
        if (c >= 112) {
            ei0[(size_t)i * DINP0 + 376 + (c - 112)] = 0;
            return;
        }
        int s = sp[i];
        if (c < 16) {
            ei0[(size_t)i * DINP0 + c] = f2bf_rn(table[s * 16 + c]);
        } else {
            int cc = c - 16;
            float acc = 0.f;
#pragma unroll
            for (int k = 0; k < 16; k++)
                acc += table[s * 16 + k] * W[k * 96 + cc];
            if (cc < 64) ei0[(size_t)i * DINP0 + 16 + cc] = f2bf_rn(acc);
            else         sd[i * 32 + cc - 64]             = acc;
        }
    } else {
        int e = (blockIdx.x - S0BLK) * 256 + threadIdx.x;
        if (e >= NEA) return;
        float d = dist[e];
        float s = sw[e];
        float rb[8];
#pragma unroll
        for (int n = 0; n < 8; n++)
            rb[n] = 0.7559289460f * __sinf((n + 1) * 0.8975979010f * d) / d * s;
        unsigned short h0[8], h1[8];
#pragma unroll
        for (int c = 0; c < 8; c++) {
            float a0 = 0.f, a1 = 0.f;
#pragma unroll
            for (int n = 0; n < 8; n++) {
                a0 += rb[n] * Wda0[n * 8 + c];
                a1 += rb[n] * Wda1[n * 8 + c];
            }
            h0[c] = f2bf_rn(a0);
            h1[c] = f2bf_rn(a1);
        }
        *(uint4*)&dah0[e * 8] = *(uint4*)h0;
        *(uint4*)&dah1[e * 8] = *(uint4*)h1;
    }
}

// ------------------------------------------------------------------
// layer 1 s: MFMA GEMM 25000x96 (ei1 bf16: A-staging is raw 16B copy)
// ------------------------------------------------------------------
__global__ __launch_bounds__(256) void k_s1(const unsigned short* __restrict__ ei1,
                                            const bf8* __restrict__ Wf,
                                            unsigned short* __restrict__ ei1o,
                                            float* __restrict__ sd) {
    __shared__ __align__(16) __bf16 Asg[4][64][8];
    int t = threadIdx.x;
    int w = t >> 6, lane = t & 63;
    int a0 = blockIdx.x * 64;

    int satom = a0 + (t >> 2);
    int k8 = (t & 3) * 8;
    const unsigned short* arow = &ei1[(size_t)satom * DINP1 + k8];
    bool aok = satom < N_ATOMS;
    int dw = (t >> 2) >> 4;
    int dl = ((t >> 2) & 15) | ((t & 3) << 4);
    __bf16* adst = &Asg[dw][dl][0];

    f4 acc[6];
#pragma unroll
    for (int j = 0; j < 6; j++) {
        f4 z = {0.f, 0.f, 0.f, 0.f};
        acc[j] = z;
    }

    for (int ch = 0; ch < 8; ch++) {
        uint4 v = make_uint4(0, 0, 0, 0);
        if (aok) v = *(const uint4*)(arow + ch * 32);
        __syncthreads();
        *(uint4*)adst = v;
        __syncthreads();
        bf8 afr = *(const bf8*)&Asg[w][lane][0];
        const bf8* wp = &Wf[(ch * 6) * 64 + lane];
#pragma unroll
        for (int tn = 0; tn < 6; tn++) {
            bf8 b = wp[tn * 64];
            acc[tn] = __builtin_amdgcn_mfma_f32_16x16x32_bf16(afr, b, acc[tn], 0, 0, 0);
        }
    }

    int nlo = lane & 15, q = lane >> 4;
#pragma unroll
    for (int r = 0; r < 4; r++) {
        int atom = a0 + w * 16 + q * 4 + r;
        if (atom < N_ATOMS) {
#pragma unroll
            for (int tn = 0; tn < 6; tn++) {
                int col = tn * 16 + nlo;
                float v = acc[tn][r];
                if (col < 64) ei1o[(size_t)atom * DINP1 + 256 + col] = f2bf_rn(v);
                else          sd[atom * 32 + col - 64] = v;
            }
        }
    }
    for (int z = t; z < 64 * 24; z += 256) {
        int za = a0 + z / 24;
        if (za < N_ATOMS) ei1o[(size_t)za * DINP1 + 616 + z % 24] = 0;
    }
}

// ------------------------------------------------------------------
// ami window helper: process up to 64 triplets held in twA (this
// wave's coalesced window), limit lim, with 1-deep dah prefetch.
// ------------------------------------------------------------------
__device__ __forceinline__ void ami_win(const float4 twA, const unsigned short* __restrict__ dah,
                                        int lim, int jj, int c,
                                        float& a0, float& a1, float& a2, float& a3, float& a4) {
    int gmax = (lim + 7) >> 3;
    float sc = 0.f; unsigned short dA = 0, dB = 0;
    {
        sc = __shfl(twA.x, jj, 64);
        int ea = __float_as_int(__shfl(twA.y, jj, 64));
        int eb = __float_as_int(__shfl(twA.z, jj, 64));
        dA = dah[ea * 8 + c];
        dB = dah[eb * 8 + c];
    }
    for (int g = 0; g < gmax; g++) {
        float scN = 0.f; unsigned short dAN = 0, dBN = 0;
        if (g + 1 < gmax) {
            int sl = (g + 1) * 8 + jj;
            scN = __shfl(twA.x, sl, 64);
            int ea = __float_as_int(__shfl(twA.y, sl, 64));
            int eb = __float_as_int(__shfl(twA.z, sl, 64));
            dAN = dah[ea * 8 + c];
            dBN = dah[eb * 8 + c];
        }
        float dij = bf2f(dA) * bf2f(dB);
        dij = (g * 8 + jj < lim) ? dij : 0.f;
        float c1 = sc;
        float c2 = __builtin_fmaf(2.f * c1, c1, -1.f);
        float c3 = __builtin_fmaf(2.f * c1, c2, -c1);
        float c4 = __builtin_fmaf(2.f * c1, c3, -c2);
        a0 += dij;
        a1 = __builtin_fmaf(c1, dij, a1);
        a2 = __builtin_fmaf(c2, dij, a2);
        a3 = __builtin_fmaf(c3, dij, a3);
        a4 = __builtin_fmaf(c4, dij, a4);
        if (g + 1 < gmax) { sc = scN; dA = dAN; dB = dBN; }
    }
}

// ------------------------------------------------------------------
// k_seg (r6-proven structure: 2 atoms/block, 2 waves/atom, LDS
// combine; r7's 4-wave split regressed — per-wave fixed overhead
// dominated). AMI blocks dispatched FIRST (they run ~2x longer than
// mi: LPT ordering packs the tail with short mi blocks). Outputs are
// bf16 (halved write traffic; consumed as bf16 by GEMM staging anyway).
// ------------------------------------------------------------------
__global__ __launch_bounds__(256) void k_seg(const int* __restrict__ eoff,
                                             const float* __restrict__ erb,
                                             const int* __restrict__ edi,
                                             const float* __restrict__ sd,
                                             unsigned short* __restrict__ mo, int mstride,
                                             const int* __restrict__ toff,
                                             const float4* __restrict__ tpay,
                                             const unsigned short* __restrict__ dah,
                                             unsigned short* __restrict__ ao, int astride) {
    __shared__ float4 smi[2][64];
    __shared__ float  sam[2][5][8];
    int t = threadIdx.x;
    int wv = t >> 6, l = t & 63;
    int slot = wv >> 1;
    int p    = wv & 1;

    if ((int)blockIdx.x < MIBLK) {
        // ---------------- ami (long blocks first) ----------------
        int i = blockIdx.x * 2 + slot;
        bool valid = (i < N_ATOMS);
        int beg = 0, end = 0;
        if (valid) { beg = toff[i]; end = toff[i + 1]; }
        int cnt = end - beg;
        int jj = l >> 3, c = l & 7;
        float a0 = 0.f, a1 = 0.f, a2 = 0.f, a3 = 0.f, a4 = 0.f;

        if (cnt > 0) {
            if (cnt <= 128) {
                int nG = (cnt + 7) >> 3;
                int h0 = (nG + 1) >> 1;          // groups for wave0
                int tb = p ? h0 * 8 : 0;         // this wave's triplet base
                int te = p ? cnt : min(h0 * 8, cnt);
                int mycnt = te - tb;
                if (mycnt > 0) {
                    float4 twA = tpay[beg + tb + min(l, mycnt - 1)];
                    ami_win(twA, dah, mycnt, jj, c, a0, a1, a2, a3, a4);
                }
            } else {
                // huge atoms: alternate 64-windows between the two waves
                int nW = (cnt + 63) >> 6;
                for (int W = p; W < nW; W += 2) {
                    int wbase = W * 64;
                    int rem = cnt - wbase;
                    int lim = min(rem, 64);
                    float4 twA = tpay[beg + wbase + min(l, rem - 1)];
                    ami_win(twA, dah, lim, jj, c, a0, a1, a2, a3, a4);
                }
            }
        }

        // reduce over jj within wave (lanes l, l^8, l^16, l^32)
#pragma unroll
        for (int msk = 8; msk <= 32; msk <<= 1) {
            a0 += __shfl_xor(a0, msk, 64);
            a1 += __shfl_xor(a1, msk, 64);
            a2 += __shfl_xor(a2, msk, 64);
            a3 += __shfl_xor(a3, msk, 64);
            a4 += __shfl_xor(a4, msk, 64);
        }
        if (p == 1 && l < 8) {
            sam[slot][0][l] = a0; sam[slot][1][l] = a1; sam[slot][2][l] = a2;
            sam[slot][3][l] = a3; sam[slot][4][l] = a4;
        }
        __syncthreads();
        if (valid && p == 0 && l < 8) {
            a0 += sam[slot][0][l]; a1 += sam[slot][1][l]; a2 += sam[slot][2][l];
            a3 += sam[slot][3][l]; a4 += sam[slot][4][l];
            unsigned short* o = &ao[(size_t)i * astride + c];
            o[0]  = f2bf_rn(a0);
            o[8]  = f2bf_rn(a1);
            o[16] = f2bf_rn(a2);
            o[24] = f2bf_rn(a3);
            o[32] = f2bf_rn(a4);
        }
    } else {
        // ---------------- mi ----------------
        int i = ((int)blockIdx.x - MIBLK) * 2 + slot;
        bool valid = (i < N_ATOMS);
        int beg = 0, end = 0;
        if (valid) { beg = eoff[i]; end = eoff[i + 1]; }
        int cnt = end - beg;
        int n = l >> 3, cb = (l & 7) * 4;
        float4 acc = make_float4(0.f, 0.f, 0.f, 0.f);

        if (cnt > 0) {
            int nG = (cnt + 7) >> 3;
            int h0 = (nG + 1) >> 1;
            int gbeg = p ? h0 : 0;
            int gend = p ? nG : h0;
            if (cnt <= 64) {
                int eWin = edi[beg + min(l, cnt - 1)];
                int cmax = end * 8 - 1;
                if (gbeg < gend) {
                    float cA = erb[min((beg + gbeg * 8) * 8 + l, cmax)];
                    for (int g = gbeg; g < gend; g++) {
                        int e8 = g * 8;
                        float4 v[8];
#pragma unroll
                        for (int j = 0; j < 8; j++) {
                            int eid = __shfl(eWin, e8 + j, 64);
                            v[j] = *(const float4*)&sd[eid * 32 + cb];
                        }
                        float cB = 0.f;
                        if (g + 1 < gend) cB = erb[min((beg + e8 + 8) * 8 + l, cmax)];
#pragma unroll
                        for (int j = 0; j < 8; j++) {
                            float r_ = __shfl(cA, j * 8 + n, 64);
                            r_ = (e8 + j < cnt) ? r_ : 0.f;
                            acc.x += r_ * v[j].x; acc.y += r_ * v[j].y;
                            acc.z += r_ * v[j].z; acc.w += r_ * v[j].w;
                        }
                        if (g + 1 < gend) cA = cB;
                    }
                }
            } else {
                // rare path (cnt > 64): direct indexed loads, same split
                const float* rp = erb + (size_t)beg * 8 + n;
                const int*   dp = edi + beg;
                for (int g = gbeg; g < gend; g++) {
                    int e8 = g * 8;
                    int m = cnt - e8;   // >= 1
#pragma unroll
                    for (int j = 0; j < 8; j++) {
                        int jj = min(j, m - 1);
                        float rb = rp[(e8 + jj) * 8];
                        int di = dp[e8 + jj];
                        if (j >= m) rb = 0.f;
                        float4 v = *(const float4*)&sd[di * 32 + cb];
                        acc.x += rb * v.x; acc.y += rb * v.y;
                        acc.z += rb * v.z; acc.w += rb * v.w;
                    }
                }
            }
        }

        if (p == 1) smi[slot][l] = acc;
        __syncthreads();
        if (valid && p == 0) {
            float4 o = smi[slot][l];
            acc.x += o.x; acc.y += o.y; acc.z += o.z; acc.w += o.w;
            ushort4 pk = make_ushort4(f2bf_rn(acc.x), f2bf_rn(acc.y),
                                      f2bf_rn(acc.z), f2bf_rn(acc.w));
            *(ushort4*)&mo[(size_t)i * mstride + l * 4] = pk;   // n*32+cb == l*4
        }
    }
}

// ------------------------------------------------------------------
// MFMA GEMM: dxi = tssr2(ei @ W + b). ei is bf16: A-staging is a raw
// 8B copy (no cvt). LAYER 0 writes bf16 ei1; LAYER 1 writes fp32 out
// with bf16 skip (residual).
// ------------------------------------------------------------------
template <int LAYER>
__global__ __launch_bounds__(256) void k_gemm(const unsigned short* __restrict__ ei,
                                              const bf8* __restrict__ Wf,
                                              const float* __restrict__ bias,
                                              const unsigned short* __restrict__ skip,
                                              float* __restrict__ outf,
                                              unsigned short* __restrict__ outb) {
    constexpr int DINP = (LAYER == 0) ? DINP0 : DINP1;
    constexpr int NCH = DINP / 32;
    __shared__ __align__(16) __bf16 Asg[2][64][8];
    int t = threadIdx.x;
    int w = t >> 6, lane = t & 63;
    int a0 = blockIdx.x * 32;

    int f  = t * 4;
    int tA = f >> 9;
    int al = (f >> 3) & 63;
    int j0 = f & 7;
    int sm = al & 15, sq = al >> 4;
    int ga = a0 + tA * 16 + sm;
    const unsigned short* arow = &ei[(size_t)ga * DINP + sq * 8 + j0];
    __bf16* adst = &Asg[0][0][0] + f;
    bool aok = (ga < N_ATOMS);

    f4 acc[2][4];
#pragma unroll
    for (int i = 0; i < 2; i++)
#pragma unroll
        for (int j = 0; j < 4; j++) {
            f4 z = {0.f, 0.f, 0.f, 0.f};
            acc[i][j] = z;
        }

    for (int ch = 0; ch < NCH; ch++) {
        uint2 v = make_uint2(0, 0);
        if (aok) v = *(const uint2*)(arow + ch * 32);
        __syncthreads();
        *(uint2*)adst = v;
        __syncthreads();
        bf8 afr0 = *(const bf8*)&Asg[0][lane][0];
        bf8 afr1 = *(const bf8*)&Asg[1][lane][0];
        const bf8* wp = &Wf[(ch * 16 + w * 4) * 64 + lane];
#pragma unroll
        for (int tn = 0; tn < 4; tn++) {
            bf8 b = wp[tn * 64];
            acc[0][tn] = __builtin_amdgcn_mfma_f32_16x16x32_bf16(afr0, b, acc[0][tn], 0, 0, 0);
            acc[1][tn] = __builtin_amdgcn_mfma_f32_16x16x32_bf16(afr1, b, acc[1][tn], 0, 0, 0);
        }
    }

    int nlo = lane & 15, q = lane >> 4;
#pragma unroll
    for (int tA2 = 0; tA2 < 2; tA2++) {
#pragma unroll
        for (int r = 0; r < 4; r++) {
            int atom = a0 + tA2 * 16 + q * 4 + r;
            if (atom < N_ATOMS) {
#pragma unroll
                for (int tn = 0; tn < 4; tn++) {
                    int col = w * 64 + tn * 16 + nlo;
                    float vv = tssr2f(acc[tA2][tn][r] + bias[col]);
                    if (LAYER == 0) {
                        outb[(size_t)atom * DINP1 + col] = f2bf_rn(vv);
                    } else {
                        outf[(size_t)atom * 256 + col] =
                            vv + bf2f(skip[(size_t)atom * DINP1 + col]);
                    }
                }
            }
        }
    }
}

// ------------------------------------------------------------------
extern "C" void kernel_launch(void* const* d_in, const int* in_sizes, int n_in,
                              void* d_out, int out_size, void* d_ws, size_t ws_size,
                              hipStream_t stream) {
    const int*   species     = (const int*)d_in[0];
    const int*   edge_src    = (const int*)d_in[1];
    const int*   edge_dst    = (const int*)d_in[2];
    const float* distances   = (const float*)d_in[3];
    const float* sw          = (const float*)d_in[4];
    const float* angles      = (const float*)d_in[5];
    const int*   angle_src   = (const int*)d_in[6];
    const int*   angle_dst   = (const int*)d_in[7];
    const int*   central     = (const int*)d_in[8];
    const float* dist_a      = (const float*)d_in[9];
    const float* sw_a        = (const float*)d_in[10];
    const float* table       = (const float*)d_in[11];
    const float* W_si0       = (const float*)d_in[12];
    const float* W_si1       = (const float*)d_in[13];
    const float* W_da0       = (const float*)d_in[14];
    const float* W_da1       = (const float*)d_in[15];
    const float* W_mix0      = (const float*)d_in[16];
    const float* b_mix0      = (const float*)d_in[17];
    const float* W_mix1      = (const float*)d_in[18];
    const float* b_mix1      = (const float*)d_in[19];
    float* out = (float*)d_out;

    char* p = (char*)d_ws;
    auto alloc = [&](size_t bytes) {
        char* r = p;
        p += (bytes + 255) & ~(size_t)255;
        return (void*)r;
    };
    unsigned short* ei0 = (unsigned short*)alloc((size_t)N_ATOMS * DINP0 * 2);
    unsigned short* ei1 = (unsigned short*)alloc((size_t)N_ATOMS * DINP1 * 2);
    float*  sd   = (float*)alloc((size_t)N_ATOMS * 32 * 4);
    unsigned short* dah0 = (unsigned short*)alloc((size_t)NEA * 8 * 2);
    unsigned short* dah1 = (unsigned short*)alloc((size_t)NEA * 8 * 2);
    float*  erbf = (float*)alloc((size_t)NE * 8 * 4);
    int*    edi  = (int*)alloc((size_t)NE * 4);
    float4* tpay = (float4*)alloc((size_t)NT * 16);
    bf8*    Wf0  = (bf8*)alloc((size_t)NFRAG0 * 16);
    bf8*    Wf1  = (bf8*)alloc((size_t)NFRAG1 * 16);
    bf8*    WfS1 = (bf8*)alloc((size_t)NFRAGS * 16);
    int* eoff   = (int*)alloc((size_t)(N_ATOMS + 1) * 4);
    int* toff   = (int*)alloc((size_t)(N_ATOMS + 1) * 4);
    int* bcnt   = (int*)alloc((size_t)2 * NBUK * 4);   // ebcnt | tbcnt (one memset)
    int* ebkoff = (int*)alloc((size_t)(NBUK + 1) * 4);
    int* tbkoff = (int*)alloc((size_t)(NBUK + 1) * 4);
    int* gce    = (int*)alloc((size_t)NBUK * 4);
    int* gct    = (int*)alloc((size_t)NBUK * 4);
    (void)ws_size;
    int* ebcnt = bcnt;
    int* tbcnt = bcnt + NBUK;

    // bucket staging aliases: ebuk on ei0 (12.8<=19.2 MB), tbuk on ei1
    // (25.6<=32 MB); both consumed by k_binB2 before ei0/ei1 are written.
    float4* ebuk = (float4*)ei0;
    float4* tbuk = (float4*)ei1;

    hipMemsetAsync(bcnt, 0, (size_t)2 * NBUK * 4, stream);

    k_wprep3<<<(NFRAG0 + NFRAG1 + NFRAGS + 255) / 256, 256, 0, stream>>>(
        W_mix0, Wf0, W_mix1, Wf1, W_si1, WfS1);

    k_bcount<<<EBLK + TBLK, 256, 0, stream>>>(edge_src, central, ebcnt, tbcnt);
    k_scanB<<<2, 512, 0, stream>>>(ebcnt, ebkoff, gce, eoff, tbcnt, tbkoff, gct, toff);

    k_binA2<<<EBLK + TBLK, 512, 0, stream>>>(
        distances, sw, edge_dst, edge_src, gce, ebuk,
        angles, angle_src, angle_dst, central, gct, tbuk);
    k_binB2<<<2 * NBUK, 256, 0, stream>>>(
        ebkoff, ebuk, erbf, edi, eoff,
        tbkoff, tbuk, tpay, toff);

    k_pre<<<S0BLK + DABLK, 256, 0, stream>>>(
        species, table, W_si0, ei0, sd,
        dist_a, sw_a, W_da0, W_da1, dah0, dah1);

    int gemm_grid = (N_ATOMS + 31) / 32;

    // ---- layer 0 ----
    k_seg<<<2 * MIBLK, 256, 0, stream>>>(eoff, erbf, edi, sd, ei0 + 80, DINP0,
                                         toff, tpay, dah0, ei0 + 336, DINP0);
    k_gemm<0><<<gemm_grid, 256, 0, stream>>>(ei0, Wf0, b_mix0, nullptr, nullptr, ei1);

    // ---- layer 1 ----
    k_s1<<<(N_ATOMS + 63) / 64, 256, 0, stream>>>(ei1, WfS1, ei1, sd);
    k_seg<<<2 * MIBLK, 256, 0, stream>>>(eoff, erbf, edi, sd, ei1 + 320, DINP1,
                                         toff, tpay, dah1, ei1 + 576, DINP1);
    k_gemm<1><<<gemm_grid, 256, 0, stream>>>(ei1, Wf1, b_mix1, ei1, out, nullptr);
}